// Round 1
// baseline (407.004 us; speedup 1.0000x reference)
//
#include <hip/hip_runtime.h>

typedef float f32x4  __attribute__((ext_vector_type(4)));
typedef _Float16 f16x8  __attribute__((ext_vector_type(8)));
typedef _Float16 f16x4v __attribute__((ext_vector_type(4)));
typedef _Float16 f16x8v __attribute__((ext_vector_type(8)));

__device__ inline void load_lds16(const _Float16* g, _Float16* l) {
    __builtin_amdgcn_global_load_lds((const __attribute__((address_space(1))) void*)g,
                                     (__attribute__((address_space(3))) void*)l, 16, 0, 0);
}

// ---------------------------------------------------------------------------
// convert_h: fp32 -> fp16 (hi only; A-side operands need no lo term)
// ---------------------------------------------------------------------------
__global__ __launch_bounds__(256)
void convert_h(const float* __restrict__ X, _Float16* __restrict__ H, long n4)
{
    long i = (long)blockIdx.x * 256 + threadIdx.x;
    if (i >= n4) return;
    f32x4 v = ((const f32x4*)X)[i];
    f16x4v h;
#pragma unroll
    for (int k = 0; k < 4; ++k) h[k] = (_Float16)v[k];
    ((f16x4v*)H)[i] = h;
}

// ---------------------------------------------------------------------------
// transpose_w3: Wq,Wk -> W2 [2048][2048] fp16 stacked-K (k<1024 hi, k>=1024 lo)
//               Wv -> Wvt [1024][1024] fp16 hi. One dispatch, z = 0/1/2.
// ---------------------------------------------------------------------------
__global__ __launch_bounds__(256)
void transpose_w3(const float* __restrict__ Wq, const float* __restrict__ Wk,
                  const float* __restrict__ Wv,
                  _Float16* __restrict__ W2, _Float16* __restrict__ Wvt, int D)
{
    const int z = blockIdx.z;
    const float* W = (z == 0) ? Wq : (z == 1) ? Wk : Wv;

    __shared__ float t[32][33];
    const int tid = threadIdx.x;
    const int bx = blockIdx.x * 32, by = blockIdx.y * 32;
    const int c = tid & 31, r0 = tid >> 5;
#pragma unroll
    for (int r = r0; r < 32; r += 8)
        t[r][c] = W[(long)(by + r) * D + bx + c];
    __syncthreads();
#pragma unroll
    for (int r = r0; r < 32; r += 8) {
        float v = t[c][r];                       // = W[by+c][bx+r]
        _Float16 h = (_Float16)v;
        if (z < 2) {
            const long nrow = (long)z * D + bx + r;      // stacked Q|K rows
            W2[nrow * 2 * D + by + c]     = h;           // hi at k
            W2[nrow * 2 * D + D + by + c] = (_Float16)(v - (float)h);  // lo at k+D
        } else {
            Wvt[(long)(bx + r) * D + by + c] = h;
        }
    }
}

// ---------------------------------------------------------------------------
// proj8: 256x256 8-phase projection GEMM (T2 swizzle + T3/T4 counted vmcnt +
// T5 setprio). 512 threads, 8 waves (1M x 8N of 32 cols), BK=64, 128KB LDS.
//   blocks 0..255 : QK, K'=2048 (A = x duplicated along K via mask,
//                   B = W2 stacked hi|lo). ct<4 -> Q epilogue, else K (hi+lo).
//   blocks 256..383: V, K=1024, transposed epilogue -> Vt [B][D][S].
// LDS swizzle: 16B granule g of row r lives at g ^ (r&7)  (both-sides, m104/
// rule 21: linear global_load_lds dest + inverse-permuted global source).
// ---------------------------------------------------------------------------
__global__ __launch_bounds__(512, 2)
void proj8(const _Float16* __restrict__ x_h, const _Float16* __restrict__ W2,
           const _Float16* __restrict__ Wvt,
           _Float16* __restrict__ Q_h, _Float16* __restrict__ K_h,
           _Float16* __restrict__ K_l, _Float16* __restrict__ Vt,
           const float* __restrict__ bq, const float* __restrict__ bk,
           const float* __restrict__ bv)
{
    constexpr int D = 1024, SEQ = 2048, BK = 64;
    __shared__ __align__(16) _Float16 lds[65536];   // 128 KB: A [0,32768) B [32768,65536)

    const int orig = blockIdx.x;
    const int bij = (orig & 7) * 48 + (orig >> 3);  // XCD swizzle (384 % 8 == 0)
    const bool isV = bij >= 256;
    int ct, rt, ldb, NT;
    const _Float16* Bb;
    if (!isV) { ct = bij & 7;  rt = bij >> 3;         Bb = W2;  ldb = 2 * D; NT = 32; }
    else      { const int b2 = bij - 256;
                ct = b2 & 3;   rt = b2 >> 2;          Bb = Wvt; ldb = D;     NT = 16; }
    const int row0 = rt * 256, col0 = ct * 256;

    const int tid = threadIdx.x;
    const int wave = tid >> 6, lane = tid & 63, l16 = lane & 15, quad = lane >> 4;
    const int wn = (wave & 3) * 32;        // window within B-half; half = wave>>2

    _Float16* SA = lds;
    _Float16* SB = lds + 32768;

    // staging: one 128x64 half-tile; phys granule p = q*512+tid (lane-linear),
    // source k pre-permuted by the read-side XOR (involution).
#define STAGEH(gb, ld, grow0, gk, dst)                                          \
    {                                                                           \
        _Pragma("unroll")                                                       \
        for (int q_ = 0; q_ < 2; ++q_) {                                        \
            const int p_ = q_ * 512 + tid;                                      \
            const int rw_ = p_ >> 3;                                            \
            const int kq_ = (p_ & 7) ^ (rw_ & 7);                               \
            load_lds16((gb) + (long)((grow0) + rw_) * (ld) + (gk) + kq_ * 8,    \
                       (dst) + p_ * 8);                                         \
        }                                                                       \
    }

    // prologue: tile 0 fully staged, drained once
    STAGEH(Bb, ldb, col0,       0, SB);
    STAGEH(Bb, ldb, col0 + 128, 0, SB + 8192);
    STAGEH(x_h, D, row0,        0, SA);
    STAGEH(x_h, D, row0 + 128,  0, SA + 8192);
    asm volatile("s_waitcnt vmcnt(0)" ::: "memory");
    __syncthreads();

    f32x4 acc[16][2] = {};

    for (int t = 0; t < NT; ++t) {
        const int cur = t & 1;
        _Float16* Ac = SA + cur * 16384;
        _Float16* Bc = SB + cur * 16384 + (wave >> 2) * 8192;
        _Float16* An = SA + (cur ^ 1) * 16384;
        _Float16* Bn = SB + (cur ^ 1) * 16384;
        const bool pf = (t + 1 < NT);
        const int kA = ((t + 1) * BK) & (D - 1);   // A duplicated along K'
        const int kB = (t + 1) * BK;

        f16x8 b[2][2];
#pragma unroll
        for (int p = 0; p < 4; ++p) {
            // --- ds reads: a-quadrant p (rows p*64 .. p*64+63), b once at p==0
            f16x8 a[4][2];
#pragma unroll
            for (int il = 0; il < 4; ++il) {
                const int lr = (p & 1) * 64 + il * 16 + l16;
#pragma unroll
                for (int kk = 0; kk < 2; ++kk)
                    a[il][kk] = *(const f16x8*)&Ac[(p >> 1) * 8192 + lr * 64 +
                                    ((((kk << 2) | quad) ^ (lr & 7)) << 3)];
            }
            if (p == 0) {
#pragma unroll
                for (int j = 0; j < 2; ++j) {
                    const int nr = wn + j * 16 + l16;
#pragma unroll
                    for (int kk = 0; kk < 2; ++kk)
                        b[j][kk] = *(const f16x8*)&Bc[nr * 64 +
                                        ((((kk << 2) | quad) ^ (nr & 7)) << 3)];
                }
            }
            // --- stage one half-tile of t+1 (B0,B1,A0,A1 over the 4 phases)
            if (pf) {
                if (p == 0) STAGEH(Bb, ldb, col0,       kB, Bn);
                if (p == 1) STAGEH(Bb, ldb, col0 + 128, kB, Bn + 8192);
                if (p == 2) STAGEH(x_h, D, row0,        kA, An);
                if (p == 3) STAGEH(x_h, D, row0 + 128,  kA, An + 8192);
            }
            // --- counted waits (never drain fresh loads):
            // p==1: A1(t) (issued 2 phases ago) must land before p2/p3 reads
            // p==3: B0,B1,A0(t+1) must land before next tile's p0 reads
            if (p == 1) {
                if (pf) asm volatile("s_waitcnt vmcnt(4)" ::: "memory");
                else    asm volatile("s_waitcnt vmcnt(0)" ::: "memory");
            }
            if (p == 3) {
                if (pf) asm volatile("s_waitcnt vmcnt(2)" ::: "memory");
                else    asm volatile("s_waitcnt vmcnt(0)" ::: "memory");
            }
            __builtin_amdgcn_s_barrier();
            asm volatile("s_waitcnt lgkmcnt(0)" ::: "memory");
            __builtin_amdgcn_sched_barrier(0);
            __builtin_amdgcn_s_setprio(1);
#pragma unroll
            for (int il = 0; il < 4; ++il)
#pragma unroll
                for (int j = 0; j < 2; ++j)
#pragma unroll
                    for (int kk = 0; kk < 2; ++kk)
                        acc[p * 4 + il][j] = __builtin_amdgcn_mfma_f32_16x16x32_f16(
                            a[il][kk], b[j][kk], acc[p * 4 + il][j], 0, 0, 0);
            __builtin_amdgcn_s_setprio(0);
            __builtin_amdgcn_s_barrier();
        }
    }

    if (!isV) {
        // ---- Q / K epilogue (tile is entirely Q or entirely K)
        const bool isQ = ct < 4;
        const float* bias = isQ ? bq : bk;
        const int cw = col0 + wave * 32;
#pragma unroll
        for (int j = 0; j < 2; ++j) {
            const int colg = cw + j * 16 + l16;
            const int cc = isQ ? colg : colg - D;
            const float bval = bias[cc];
#pragma unroll
            for (int ig = 0; ig < 16; ++ig) {
                const int rb = row0 + ig * 16 + quad * 4;
#pragma unroll
                for (int r = 0; r < 4; ++r) {
                    const float v = acc[ig][j][r] + bval;
                    const _Float16 h = (_Float16)v;
                    if (isQ) {
                        Q_h[(long)(rb + r) * D + cc] = h;
                    } else {
                        K_h[(long)(rb + r) * D + cc] = h;
                        K_l[(long)(rb + r) * D + cc] = (_Float16)(v - (float)h);
                    }
                }
            }
        }
    } else {
        // ---- V epilogue: transpose via LDS (reuse all 128 KB), XOR-swizzled
        _Float16* sVt = lds;                 // [256 cols][256 rows] fp16
        const int cw = wave * 32;
#pragma unroll
        for (int j = 0; j < 2; ++j) {
            const int cl = cw + j * 16 + l16;
            const float bval = bv[col0 + cl];
#pragma unroll
            for (int ig = 0; ig < 16; ++ig) {
                f16x4v pk;
#pragma unroll
                for (int r = 0; r < 4; ++r) pk[r] = (_Float16)(acc[ig][j][r] + bval);
                const int sb = cl * 512 + ((ig * 32 + quad * 8) ^ ((cl & 31) << 4));
                *(f16x4v*)((char*)sVt + sb) = pk;
            }
        }
        __syncthreads();
        const int bb = row0 >> 11;           // tiles never cross batches
        const int s0 = row0 & (SEQ - 1);
        for (int idx = tid; idx < 8192; idx += 512) {
            const int cl = idx >> 5, r8 = idx & 31;
            const int sb = cl * 512 + ((r8 * 16) ^ ((cl & 31) << 4));
            f16x8v v = *(const f16x8v*)((char*)sVt + sb);
            *(f16x8v*)&Vt[((long)bb * D + col0 + cl) * SEQ + s0 + r8 * 8] = v;
        }
    }
#undef STAGEH
}

// ---------------------------------------------------------------------------
// gemm2: C = A @ B^T_layout (fp32 out). A fp16 [M][K] (hi only),
// B fp16 [N][K] hi (+ lo if BLO: 2-term accumulate). TM=128 x TNB, TK=32.
// MODE 1: causal packed triangular grid (x = live-tile id, TNB=64);
// MODE 2: PV, grid (x=rows heavy-first, y=cols), K bounded at (rt+1)*TM.
// ---------------------------------------------------------------------------
constexpr int TM = 128, TK = 32;

template<bool BLO, int MODE, int TNB>
__global__ __launch_bounds__(256)
void gemm2(const _Float16* __restrict__ Ah, long sA, int lda,
           const _Float16* __restrict__ Bh, const _Float16* __restrict__ Bl,
           long sB, int ldb,
           float* __restrict__ Cf, long sC, int ldc, int K)
{
    static_assert(MODE != 1 || TNB == 64, "packed causal decode assumes TNB=64");
    constexpr int NFJ = TNB / 32;
    constexpr int BRNDS = TNB / 64;

    int rt, ct;
    if (MODE == 1) {
        const int t = blockIdx.x;
        rt = (int)((sqrtf(4.0f * t + 1.0f) - 1.0f) * 0.5f);
        while (rt * (rt + 1) > t) --rt;
        while ((rt + 1) * (rt + 2) <= t) ++rt;
        ct = t - rt * (rt + 1);
    } else {
        rt = (gridDim.x - 1) - blockIdx.x;   // heavy rows first
        ct = blockIdx.y;
    }
    const int bz = blockIdx.z;

    const _Float16* gAh = Ah + (long)bz * sA;
    const _Float16* gBh = Bh + (long)bz * sB;
    const _Float16* gBl = BLO ? Bl + (long)bz * sB : nullptr;

    const int row0 = rt * TM, col0 = ct * TNB;
    const int k_end = (MODE == 2) ? min(K, (rt + 1) * TM) : K;

    __shared__ _Float16 sAh[TM * TK];
    __shared__ _Float16 sBh[TNB * TK];
    __shared__ _Float16 sBl[BLO ? TNB * TK : 8];

    const int tid = threadIdx.x;
    const int lane = tid & 63, wave = tid >> 6;
    const int l16 = lane & 15, quad = lane >> 4;
    const int wm = (wave >> 1) * 64, wn = (wave & 1) * (TNB / 2);

    f32x4 acc[4][NFJ] = {};

    for (int k0 = 0; k0 < k_end; k0 += TK) {
#pragma unroll
        for (int rnd = 0; rnd < 2; ++rnd) {
            const int row = rnd * 64 + (tid >> 2);
            const long gA = (long)(row0 + row) * lda + k0 + (tid & 3) * 8;
            load_lds16(gAh + gA, sAh + rnd * 2048 + tid * 8);
        }
#pragma unroll
        for (int rnd = 0; rnd < BRNDS; ++rnd) {
            const int row = rnd * 64 + (tid >> 2);
            const long gB = (long)(col0 + row) * ldb + k0 + (tid & 3) * 8;
            const int lofs = rnd * 2048 + tid * 8;
            load_lds16(gBh + gB, sBh + lofs);
            if (BLO) load_lds16(gBl + gB, sBl + lofs);
        }
        __syncthreads();

        f16x8 a[4], b_h[NFJ];
#pragma unroll
        for (int i = 0; i < 4; ++i)
            a[i] = *(const f16x8*)&sAh[(wm + i * 16 + l16) * TK + (quad << 3)];
#pragma unroll
        for (int j = 0; j < NFJ; ++j)
            b_h[j] = *(const f16x8*)&sBh[(wn + j * 16 + l16) * TK + (quad << 3)];

        if (BLO) {
            f16x8 b_l[NFJ];
#pragma unroll
            for (int j = 0; j < NFJ; ++j)
                b_l[j] = *(const f16x8*)&sBl[(wn + j * 16 + l16) * TK + (quad << 3)];
#pragma unroll
            for (int i = 0; i < 4; ++i)
#pragma unroll
                for (int j = 0; j < NFJ; ++j) {
                    acc[i][j] = __builtin_amdgcn_mfma_f32_16x16x32_f16(a[i], b_h[j], acc[i][j], 0, 0, 0);
                    acc[i][j] = __builtin_amdgcn_mfma_f32_16x16x32_f16(a[i], b_l[j], acc[i][j], 0, 0, 0);
                }
        } else {
#pragma unroll
            for (int i = 0; i < 4; ++i)
#pragma unroll
                for (int j = 0; j < NFJ; ++j)
                    acc[i][j] = __builtin_amdgcn_mfma_f32_16x16x32_f16(a[i], b_h[j], acc[i][j], 0, 0, 0);
        }
        __syncthreads();
    }

    float* cf = Cf + (long)bz * sC;
#pragma unroll
    for (int j = 0; j < NFJ; ++j) {
        const int col = col0 + wn + j * 16 + l16;
#pragma unroll
        for (int i = 0; i < 4; ++i) {
            const int rb = row0 + wm + i * 16 + quad * 4;
#pragma unroll
            for (int r = 0; r < 4; ++r)
                cf[(long)(rb + r) * ldc + col] = acc[i][j][r];
        }
    }
}

// ---------------------------------------------------------------------------
// softmax: causal, fp32 Sc row -> fp16 P row; loads only live 32B chunks,
// writes exactly the columns the PV GEMM will read (ceil((r+1)/128)*128).
// ---------------------------------------------------------------------------
__global__ __launch_bounds__(256)
void softmax_kernel(const float* __restrict__ Sc, _Float16* __restrict__ P, int seq)
{
    const int r = blockIdx.x, b = blockIdx.y;
    const float* row = Sc + ((long)b * seq + r) * seq;
    _Float16* prow = P + ((long)b * seq + r) * seq;
    const int tid = threadIdx.x;
    const int cmax = ((r >> 7) + 1) << 7;
    const int c0 = tid * 8;

    float v[8];
    f32x4 v0, v1;
    if (c0 <= r) {                 // chunk has at least one live column
        const f32x4* rp = (const f32x4*)row;
        v0 = rp[tid * 2];
        v1 = rp[tid * 2 + 1];
    } else {
        v0 = (f32x4)(-3.0e38f);
        v1 = (f32x4)(-3.0e38f);
    }
    float lmax = -3.0e38f;
#pragma unroll
    for (int k = 0; k < 4; ++k) {
        v[k]     = (c0 + k     <= r) ? v0[k] : -3.0e38f;
        v[k + 4] = (c0 + k + 4 <= r) ? v1[k] : -3.0e38f;
    }
#pragma unroll
    for (int k = 0; k < 8; ++k) lmax = fmaxf(lmax, v[k]);

    __shared__ float red[256];
    red[tid] = lmax; __syncthreads();
    for (int s = 128; s > 0; s >>= 1) {
        if (tid < s) red[tid] = fmaxf(red[tid], red[tid + s]);
        __syncthreads();
    }
    const float m = red[0];
    __syncthreads();

    float lsum = 0.0f;
#pragma unroll
    for (int k = 0; k < 8; ++k) {
        float e = (v[k] > -1.0e38f) ? __expf(v[k] - m) : 0.0f;
        v[k] = e;
        lsum += e;
    }
    red[tid] = lsum; __syncthreads();
    for (int s = 128; s > 0; s >>= 1) {
        if (tid < s) red[tid] += red[tid + s];
        __syncthreads();
    }
    const float inv = 1.0f / red[0];

    if (c0 < cmax) {
        f16x8v o;
#pragma unroll
        for (int k = 0; k < 8; ++k) o[k] = (_Float16)(v[k] * inv);
        ((f16x8v*)prow)[tid] = o;
    }
}

// ---------------------------------------------------------------------------
extern "C" void kernel_launch(void* const* d_in, const int* in_sizes, int n_in,
                              void* d_out, int out_size, void* d_ws, size_t ws_size,
                              hipStream_t stream)
{
    constexpr int B = 4, S = 2048, D = 1024;
    constexpr long MB = 1024 * 1024;
    const float* x  = (const float*)d_in[0];
    const float* Wq = (const float*)d_in[1];
    const float* bq = (const float*)d_in[2];
    const float* Wk = (const float*)d_in[3];
    const float* bk = (const float*)d_in[4];
    const float* Wv = (const float*)d_in[5];
    const float* bv = (const float*)d_in[6];
    float* out = (float*)d_out;

    // workspace layout (160 MB; Sc overlaps dead x/W regions)
    char* ws = (char*)d_ws;
    _Float16* x_h   = (_Float16*)(ws + 0);         // 16 MB
    _Float16* W2    = (_Float16*)(ws + 16 * MB);   // 8 MB [2048][2048] hi|lo stacked-K
    _Float16* Wvt_h = (_Float16*)(ws + 24 * MB);   // 2 MB [1024][1024]
    float*    Sc    = (float*)(ws + 0);            // 64 MB, after x/W dead
    _Float16* Q_h   = (_Float16*)(ws + 64 * MB);   // 16 MB [M][1024]
    _Float16* K_h   = (_Float16*)(ws + 80 * MB);   // 16 MB
    _Float16* K_l   = (_Float16*)(ws + 96 * MB);   // 16 MB
    _Float16* Vt    = (_Float16*)(ws + 112 * MB);  // 16 MB [B][D][S]
    _Float16* P     = (_Float16*)(ws + 128 * MB);  // 32 MB [B][S][S]

    const int M = B * S;  // 8192
    dim3 blk(256);

    // 1) convert x -> fp16 hi (A-side needs no lo)
    convert_h<<<(M * D / 4 + 255) / 256, blk, 0, stream>>>(x, x_h, (long)M * D / 4);
    // 2) weight transposes: Wq|Wk hi/lo stacked along K into W2; Wv hi into Wvt
    transpose_w3<<<dim3(D / 32, D / 32, 3), blk, 0, stream>>>(
        Wq, Wk, Wv, W2, Wvt_h, D);

    // 3) 8-phase 256x256 projections: blocks 0-255 QK (K'=2048), 256-383 V
    proj8<<<dim3(384), dim3(512), 0, stream>>>(
        x_h, W2, Wvt_h, Q_h, K_h, K_l, Vt, bq, bk, bv);

    // 4) scores = Q_h @ (K_h + K_l)^T (2-term, packed triangular, TN=64) -> fp32
    const int ntiles = (S / TM) * (S / TM + 1);   // 272 live 128x64 tiles
    gemm2<true, 1, 64><<<dim3(ntiles, 1, B), blk, 0, stream>>>(
        Q_h, (long)S * D, D, K_h, K_l, (long)S * D, D,
        Sc, (long)S * S, S, D);

    // 5) causal softmax: fp32 Sc -> fp16 P
    softmax_kernel<<<dim3(S, B), blk, 0, stream>>>(Sc, P, S);

    // 6) out = P @ V (K-loop bounded at diagonal, heavy rows first, TN=64)
    gemm2<false, 2, 64><<<dim3(S / TM, D / 64, B), blk, 0, stream>>>(
        P, (long)S * S, S, Vt, nullptr, (long)D * S, S,
        out, (long)S * D, D, S);
}

// Round 2
// 395.231 us; speedup vs baseline: 1.0298x; 1.0298x over previous
//
#include <hip/hip_runtime.h>

typedef float f32x4  __attribute__((ext_vector_type(4)));
typedef _Float16 f16x8  __attribute__((ext_vector_type(8)));
typedef _Float16 f16x4v __attribute__((ext_vector_type(4)));
typedef _Float16 f16x8v __attribute__((ext_vector_type(8)));

__device__ inline void load_lds16(const _Float16* g, _Float16* l) {
    __builtin_amdgcn_global_load_lds((const __attribute__((address_space(1))) void*)g,
                                     (__attribute__((address_space(3))) void*)l, 16, 0, 0);
}

// ---------------------------------------------------------------------------
// convert_h: fp32 -> fp16 (hi only; A-side operands need no lo term)
// ---------------------------------------------------------------------------
__global__ __launch_bounds__(256)
void convert_h(const float* __restrict__ X, _Float16* __restrict__ H, long n4)
{
    long i = (long)blockIdx.x * 256 + threadIdx.x;
    if (i >= n4) return;
    f32x4 v = ((const f32x4*)X)[i];
    f16x4v h;
#pragma unroll
    for (int k = 0; k < 4; ++k) h[k] = (_Float16)v[k];
    ((f16x4v*)H)[i] = h;
}

// ---------------------------------------------------------------------------
// transpose_w3: Wq,Wk -> W2 [2048][2048] fp16 stacked-K (k<1024 hi, k>=1024 lo)
//               Wv -> Wvt [1024][1024] fp16 hi. One dispatch, z = 0/1/2.
// ---------------------------------------------------------------------------
__global__ __launch_bounds__(256)
void transpose_w3(const float* __restrict__ Wq, const float* __restrict__ Wk,
                  const float* __restrict__ Wv,
                  _Float16* __restrict__ W2, _Float16* __restrict__ Wvt, int D)
{
    const int z = blockIdx.z;
    const float* W = (z == 0) ? Wq : (z == 1) ? Wk : Wv;

    __shared__ float t[32][33];
    const int tid = threadIdx.x;
    const int bx = blockIdx.x * 32, by = blockIdx.y * 32;
    const int c = tid & 31, r0 = tid >> 5;
#pragma unroll
    for (int r = r0; r < 32; r += 8)
        t[r][c] = W[(long)(by + r) * D + bx + c];
    __syncthreads();
#pragma unroll
    for (int r = r0; r < 32; r += 8) {
        float v = t[c][r];                       // = W[by+c][bx+r]
        _Float16 h = (_Float16)v;
        if (z < 2) {
            const long nrow = (long)z * D + bx + r;      // stacked Q|K rows
            W2[nrow * 2 * D + by + c]     = h;           // hi at k
            W2[nrow * 2 * D + D + by + c] = (_Float16)(v - (float)h);  // lo at k+D
        } else {
            Wvt[(long)(bx + r) * D + by + c] = h;
        }
    }
}

// ---------------------------------------------------------------------------
// proj8: 256x256 8-phase projection GEMM (T2 swizzle + T3/T4 counted vmcnt +
// T5 setprio). 512 threads, 8 waves (1M x 8N of 32 cols), BK=64, 128KB LDS.
//   blocks 0..255 : QK, K'=2048 (A = x duplicated along K via mask,
//                   B = W2 stacked hi|lo). ct<4 -> Q epilogue, else K (hi+lo).
//   blocks 256..383: V, K=1024, transposed epilogue -> Vt [B][D][S].
// LDS swizzle: 16B granule g of row r lives at g ^ (r&7)  (both-sides, m104/
// rule 21: linear global_load_lds dest + inverse-permuted global source).
// NOTE: __launch_bounds__(512) ONLY — a min-waves/EU of 2 caps VGPR at 128,
// which forces the 128-float accumulator into scratch (R0 post-mortem:
// WRITE_SIZE 139MB vs 64MB logical = spill traffic). 512 threads already
// implies 2 waves/SIMD residency => 256-VGPR cap, which fits ~200 live.
// ---------------------------------------------------------------------------
__global__ __launch_bounds__(512)
void proj8(const _Float16* __restrict__ x_h, const _Float16* __restrict__ W2,
           const _Float16* __restrict__ Wvt,
           _Float16* __restrict__ Q_h, _Float16* __restrict__ K_h,
           _Float16* __restrict__ K_l, _Float16* __restrict__ Vt,
           const float* __restrict__ bq, const float* __restrict__ bk,
           const float* __restrict__ bv)
{
    constexpr int D = 1024, SEQ = 2048, BK = 64;
    __shared__ __align__(16) _Float16 lds[65536];   // 128 KB: A [0,32768) B [32768,65536)

    const int orig = blockIdx.x;
    const int bij = (orig & 7) * 48 + (orig >> 3);  // XCD swizzle (384 % 8 == 0)
    const bool isV = bij >= 256;
    int ct, rt, ldb, NT;
    const _Float16* Bb;
    if (!isV) { ct = bij & 7;  rt = bij >> 3;         Bb = W2;  ldb = 2 * D; NT = 32; }
    else      { const int b2 = bij - 256;
                ct = b2 & 3;   rt = b2 >> 2;          Bb = Wvt; ldb = D;     NT = 16; }
    const int row0 = rt * 256, col0 = ct * 256;

    const int tid = threadIdx.x;
    const int wave = tid >> 6, lane = tid & 63, l16 = lane & 15, quad = lane >> 4;
    const int wn = (wave & 3) * 32;        // window within B-half; half = wave>>2

    _Float16* SA = lds;
    _Float16* SB = lds + 32768;

    // staging: one 128x64 half-tile; phys granule p = q*512+tid (lane-linear),
    // source k pre-permuted by the read-side XOR (involution).
#define STAGEH(gb, ld, grow0, gk, dst)                                          \
    {                                                                           \
        _Pragma("unroll")                                                       \
        for (int q_ = 0; q_ < 2; ++q_) {                                        \
            const int p_ = q_ * 512 + tid;                                      \
            const int rw_ = p_ >> 3;                                            \
            const int kq_ = (p_ & 7) ^ (rw_ & 7);                               \
            load_lds16((gb) + (long)((grow0) + rw_) * (ld) + (gk) + kq_ * 8,    \
                       (dst) + p_ * 8);                                         \
        }                                                                       \
    }

    // prologue: tile 0 fully staged, drained once
    STAGEH(Bb, ldb, col0,       0, SB);
    STAGEH(Bb, ldb, col0 + 128, 0, SB + 8192);
    STAGEH(x_h, D, row0,        0, SA);
    STAGEH(x_h, D, row0 + 128,  0, SA + 8192);
    asm volatile("s_waitcnt vmcnt(0)" ::: "memory");
    __syncthreads();

    f32x4 acc[16][2] = {};

    for (int t = 0; t < NT; ++t) {
        const int cur = t & 1;
        _Float16* Ac = SA + cur * 16384;
        _Float16* Bc = SB + cur * 16384 + (wave >> 2) * 8192;
        _Float16* An = SA + (cur ^ 1) * 16384;
        _Float16* Bn = SB + (cur ^ 1) * 16384;
        const bool pf = (t + 1 < NT);
        const int kA = ((t + 1) * BK) & (D - 1);   // A duplicated along K'
        const int kB = (t + 1) * BK;

        f16x8 b[2][2];
#pragma unroll
        for (int p = 0; p < 4; ++p) {
            // --- ds reads: a-quadrant p (rows p*64 .. p*64+63), b once at p==0
            f16x8 a[4][2];
#pragma unroll
            for (int il = 0; il < 4; ++il) {
                const int lr = (p & 1) * 64 + il * 16 + l16;
#pragma unroll
                for (int kk = 0; kk < 2; ++kk)
                    a[il][kk] = *(const f16x8*)&Ac[(p >> 1) * 8192 + lr * 64 +
                                    ((((kk << 2) | quad) ^ (lr & 7)) << 3)];
            }
            if (p == 0) {
#pragma unroll
                for (int j = 0; j < 2; ++j) {
                    const int nr = wn + j * 16 + l16;
#pragma unroll
                    for (int kk = 0; kk < 2; ++kk)
                        b[j][kk] = *(const f16x8*)&Bc[nr * 64 +
                                        ((((kk << 2) | quad) ^ (nr & 7)) << 3)];
                }
            }
            // --- stage one half-tile of t+1 (B0,B1,A0,A1 over the 4 phases)
            if (pf) {
                if (p == 0) STAGEH(Bb, ldb, col0,       kB, Bn);
                if (p == 1) STAGEH(Bb, ldb, col0 + 128, kB, Bn + 8192);
                if (p == 2) STAGEH(x_h, D, row0,        kA, An);
                if (p == 3) STAGEH(x_h, D, row0 + 128,  kA, An + 8192);
            }
            // --- counted waits (never drain fresh loads):
            // p==1: A1(t) (issued 2 phases ago) must land before p2/p3 reads
            // p==3: B0,B1,A0(t+1) must land before next tile's p0 reads
            if (p == 1) {
                if (pf) asm volatile("s_waitcnt vmcnt(4)" ::: "memory");
                else    asm volatile("s_waitcnt vmcnt(0)" ::: "memory");
            }
            if (p == 3) {
                if (pf) asm volatile("s_waitcnt vmcnt(2)" ::: "memory");
                else    asm volatile("s_waitcnt vmcnt(0)" ::: "memory");
            }
            __builtin_amdgcn_s_barrier();
            asm volatile("s_waitcnt lgkmcnt(0)" ::: "memory");
            __builtin_amdgcn_sched_barrier(0);
            __builtin_amdgcn_s_setprio(1);
#pragma unroll
            for (int il = 0; il < 4; ++il)
#pragma unroll
                for (int j = 0; j < 2; ++j)
#pragma unroll
                    for (int kk = 0; kk < 2; ++kk)
                        acc[p * 4 + il][j] = __builtin_amdgcn_mfma_f32_16x16x32_f16(
                            a[il][kk], b[j][kk], acc[p * 4 + il][j], 0, 0, 0);
            __builtin_amdgcn_s_setprio(0);
            __builtin_amdgcn_s_barrier();
        }
    }

    if (!isV) {
        // ---- Q / K epilogue (tile is entirely Q or entirely K)
        const bool isQ = ct < 4;
        const float* bias = isQ ? bq : bk;
        const int cw = col0 + wave * 32;
#pragma unroll
        for (int j = 0; j < 2; ++j) {
            const int colg = cw + j * 16 + l16;
            const int cc = isQ ? colg : colg - D;
            const float bval = bias[cc];
#pragma unroll
            for (int ig = 0; ig < 16; ++ig) {
                const int rb = row0 + ig * 16 + quad * 4;
#pragma unroll
                for (int r = 0; r < 4; ++r) {
                    const float v = acc[ig][j][r] + bval;
                    const _Float16 h = (_Float16)v;
                    if (isQ) {
                        Q_h[(long)(rb + r) * D + cc] = h;
                    } else {
                        K_h[(long)(rb + r) * D + cc] = h;
                        K_l[(long)(rb + r) * D + cc] = (_Float16)(v - (float)h);
                    }
                }
            }
        }
    } else {
        // ---- V epilogue: transpose via LDS (reuse all 128 KB), XOR-swizzled
        _Float16* sVt = lds;                 // [256 cols][256 rows] fp16
        const int cw = wave * 32;
#pragma unroll
        for (int j = 0; j < 2; ++j) {
            const int cl = cw + j * 16 + l16;
            const float bval = bv[col0 + cl];
#pragma unroll
            for (int ig = 0; ig < 16; ++ig) {
                f16x4v pk;
#pragma unroll
                for (int r = 0; r < 4; ++r) pk[r] = (_Float16)(acc[ig][j][r] + bval);
                const int sb = cl * 512 + ((ig * 32 + quad * 8) ^ ((cl & 31) << 4));
                *(f16x4v*)((char*)sVt + sb) = pk;
            }
        }
        __syncthreads();
        const int bb = row0 >> 11;           // tiles never cross batches
        const int s0 = row0 & (SEQ - 1);
        for (int idx = tid; idx < 8192; idx += 512) {
            const int cl = idx >> 5, r8 = idx & 31;
            const int sb = cl * 512 + ((r8 * 16) ^ ((cl & 31) << 4));
            f16x8v v = *(const f16x8v*)((char*)sVt + sb);
            *(f16x8v*)&Vt[((long)bb * D + col0 + cl) * SEQ + s0 + r8 * 8] = v;
        }
    }
#undef STAGEH
}

// ---------------------------------------------------------------------------
// gemm2: C = A @ B^T_layout (fp32 out). A fp16 [M][K] (hi only),
// B fp16 [N][K] hi (+ lo if BLO: 2-term accumulate). TM=128 x TNB, TK=32.
// MODE 1: causal packed triangular grid (x = live-tile id, TNB=64);
// MODE 2: PV, grid (x=rows heavy-first, y=cols), K bounded at (rt+1)*TM.
// ---------------------------------------------------------------------------
constexpr int TM = 128, TK = 32;

template<bool BLO, int MODE, int TNB>
__global__ __launch_bounds__(256)
void gemm2(const _Float16* __restrict__ Ah, long sA, int lda,
           const _Float16* __restrict__ Bh, const _Float16* __restrict__ Bl,
           long sB, int ldb,
           float* __restrict__ Cf, long sC, int ldc, int K)
{
    static_assert(MODE != 1 || TNB == 64, "packed causal decode assumes TNB=64");
    constexpr int NFJ = TNB / 32;
    constexpr int BRNDS = TNB / 64;

    int rt, ct;
    if (MODE == 1) {
        const int t = blockIdx.x;
        rt = (int)((sqrtf(4.0f * t + 1.0f) - 1.0f) * 0.5f);
        while (rt * (rt + 1) > t) --rt;
        while ((rt + 1) * (rt + 2) <= t) ++rt;
        ct = t - rt * (rt + 1);
    } else {
        rt = (gridDim.x - 1) - blockIdx.x;   // heavy rows first
        ct = blockIdx.y;
    }
    const int bz = blockIdx.z;

    const _Float16* gAh = Ah + (long)bz * sA;
    const _Float16* gBh = Bh + (long)bz * sB;
    const _Float16* gBl = BLO ? Bl + (long)bz * sB : nullptr;

    const int row0 = rt * TM, col0 = ct * TNB;
    const int k_end = (MODE == 2) ? min(K, (rt + 1) * TM) : K;

    __shared__ _Float16 sAh[TM * TK];
    __shared__ _Float16 sBh[TNB * TK];
    __shared__ _Float16 sBl[BLO ? TNB * TK : 8];

    const int tid = threadIdx.x;
    const int lane = tid & 63, wave = tid >> 6;
    const int l16 = lane & 15, quad = lane >> 4;
    const int wm = (wave >> 1) * 64, wn = (wave & 1) * (TNB / 2);

    f32x4 acc[4][NFJ] = {};

    for (int k0 = 0; k0 < k_end; k0 += TK) {
#pragma unroll
        for (int rnd = 0; rnd < 2; ++rnd) {
            const int row = rnd * 64 + (tid >> 2);
            const long gA = (long)(row0 + row) * lda + k0 + (tid & 3) * 8;
            load_lds16(gAh + gA, sAh + rnd * 2048 + tid * 8);
        }
#pragma unroll
        for (int rnd = 0; rnd < BRNDS; ++rnd) {
            const int row = rnd * 64 + (tid >> 2);
            const long gB = (long)(col0 + row) * ldb + k0 + (tid & 3) * 8;
            const int lofs = rnd * 2048 + tid * 8;
            load_lds16(gBh + gB, sBh + lofs);
            if (BLO) load_lds16(gBl + gB, sBl + lofs);
        }
        __syncthreads();

        f16x8 a[4], b_h[NFJ];
#pragma unroll
        for (int i = 0; i < 4; ++i)
            a[i] = *(const f16x8*)&sAh[(wm + i * 16 + l16) * TK + (quad << 3)];
#pragma unroll
        for (int j = 0; j < NFJ; ++j)
            b_h[j] = *(const f16x8*)&sBh[(wn + j * 16 + l16) * TK + (quad << 3)];

        if (BLO) {
            f16x8 b_l[NFJ];
#pragma unroll
            for (int j = 0; j < NFJ; ++j)
                b_l[j] = *(const f16x8*)&sBl[(wn + j * 16 + l16) * TK + (quad << 3)];
#pragma unroll
            for (int i = 0; i < 4; ++i)
#pragma unroll
                for (int j = 0; j < NFJ; ++j) {
                    acc[i][j] = __builtin_amdgcn_mfma_f32_16x16x32_f16(a[i], b_h[j], acc[i][j], 0, 0, 0);
                    acc[i][j] = __builtin_amdgcn_mfma_f32_16x16x32_f16(a[i], b_l[j], acc[i][j], 0, 0, 0);
                }
        } else {
#pragma unroll
            for (int i = 0; i < 4; ++i)
#pragma unroll
                for (int j = 0; j < NFJ; ++j)
                    acc[i][j] = __builtin_amdgcn_mfma_f32_16x16x32_f16(a[i], b_h[j], acc[i][j], 0, 0, 0);
        }
        __syncthreads();
    }

    float* cf = Cf + (long)bz * sC;
#pragma unroll
    for (int j = 0; j < NFJ; ++j) {
        const int col = col0 + wn + j * 16 + l16;
#pragma unroll
        for (int i = 0; i < 4; ++i) {
            const int rb = row0 + wm + i * 16 + quad * 4;
#pragma unroll
            for (int r = 0; r < 4; ++r)
                cf[(long)(rb + r) * ldc + col] = acc[i][j][r];
        }
    }
}

// ---------------------------------------------------------------------------
// softmax: causal, fp32 Sc row -> fp16 P row; loads only live 32B chunks,
// writes exactly the columns the PV GEMM will read (ceil((r+1)/128)*128).
// ---------------------------------------------------------------------------
__global__ __launch_bounds__(256)
void softmax_kernel(const float* __restrict__ Sc, _Float16* __restrict__ P, int seq)
{
    const int r = blockIdx.x, b = blockIdx.y;
    const float* row = Sc + ((long)b * seq + r) * seq;
    _Float16* prow = P + ((long)b * seq + r) * seq;
    const int tid = threadIdx.x;
    const int cmax = ((r >> 7) + 1) << 7;
    const int c0 = tid * 8;

    float v[8];
    f32x4 v0, v1;
    if (c0 <= r) {                 // chunk has at least one live column
        const f32x4* rp = (const f32x4*)row;
        v0 = rp[tid * 2];
        v1 = rp[tid * 2 + 1];
    } else {
        v0 = (f32x4)(-3.0e38f);
        v1 = (f32x4)(-3.0e38f);
    }
    float lmax = -3.0e38f;
#pragma unroll
    for (int k = 0; k < 4; ++k) {
        v[k]     = (c0 + k     <= r) ? v0[k] : -3.0e38f;
        v[k + 4] = (c0 + k + 4 <= r) ? v1[k] : -3.0e38f;
    }
#pragma unroll
    for (int k = 0; k < 8; ++k) lmax = fmaxf(lmax, v[k]);

    __shared__ float red[256];
    red[tid] = lmax; __syncthreads();
    for (int s = 128; s > 0; s >>= 1) {
        if (tid < s) red[tid] = fmaxf(red[tid], red[tid + s]);
        __syncthreads();
    }
    const float m = red[0];
    __syncthreads();

    float lsum = 0.0f;
#pragma unroll
    for (int k = 0; k < 8; ++k) {
        float e = (v[k] > -1.0e38f) ? __expf(v[k] - m) : 0.0f;
        v[k] = e;
        lsum += e;
    }
    red[tid] = lsum; __syncthreads();
    for (int s = 128; s > 0; s >>= 1) {
        if (tid < s) red[tid] += red[tid + s];
        __syncthreads();
    }
    const float inv = 1.0f / red[0];

    if (c0 < cmax) {
        f16x8v o;
#pragma unroll
        for (int k = 0; k < 8; ++k) o[k] = (_Float16)(v[k] * inv);
        ((f16x8v*)prow)[tid] = o;
    }
}

// ---------------------------------------------------------------------------
extern "C" void kernel_launch(void* const* d_in, const int* in_sizes, int n_in,
                              void* d_out, int out_size, void* d_ws, size_t ws_size,
                              hipStream_t stream)
{
    constexpr int B = 4, S = 2048, D = 1024;
    constexpr long MB = 1024 * 1024;
    const float* x  = (const float*)d_in[0];
    const float* Wq = (const float*)d_in[1];
    const float* bq = (const float*)d_in[2];
    const float* Wk = (const float*)d_in[3];
    const float* bk = (const float*)d_in[4];
    const float* Wv = (const float*)d_in[5];
    const float* bv = (const float*)d_in[6];
    float* out = (float*)d_out;

    // workspace layout (160 MB; Sc overlaps dead x/W regions)
    char* ws = (char*)d_ws;
    _Float16* x_h   = (_Float16*)(ws + 0);         // 16 MB
    _Float16* W2    = (_Float16*)(ws + 16 * MB);   // 8 MB [2048][2048] hi|lo stacked-K
    _Float16* Wvt_h = (_Float16*)(ws + 24 * MB);   // 2 MB [1024][1024]
    float*    Sc    = (float*)(ws + 0);            // 64 MB, after x/W dead
    _Float16* Q_h   = (_Float16*)(ws + 64 * MB);   // 16 MB [M][1024]
    _Float16* K_h   = (_Float16*)(ws + 80 * MB);   // 16 MB
    _Float16* K_l   = (_Float16*)(ws + 96 * MB);   // 16 MB
    _Float16* Vt    = (_Float16*)(ws + 112 * MB);  // 16 MB [B][D][S]
    _Float16* P     = (_Float16*)(ws + 128 * MB);  // 32 MB [B][S][S]

    const int M = B * S;  // 8192
    dim3 blk(256);

    // 1) convert x -> fp16 hi (A-side needs no lo)
    convert_h<<<(M * D / 4 + 255) / 256, blk, 0, stream>>>(x, x_h, (long)M * D / 4);
    // 2) weight transposes: Wq|Wk hi/lo stacked along K into W2; Wv hi into Wvt
    transpose_w3<<<dim3(D / 32, D / 32, 3), blk, 0, stream>>>(
        Wq, Wk, Wv, W2, Wvt_h, D);

    // 3) 8-phase 256x256 projections: blocks 0-255 QK (K'=2048), 256-383 V
    proj8<<<dim3(384), dim3(512), 0, stream>>>(
        x_h, W2, Wvt_h, Q_h, K_h, K_l, Vt, bq, bk, bv);

    // 4) scores = Q_h @ (K_h + K_l)^T (2-term, packed triangular, TN=64) -> fp32
    const int ntiles = (S / TM) * (S / TM + 1);   // 272 live 128x64 tiles
    gemm2<true, 1, 64><<<dim3(ntiles, 1, B), blk, 0, stream>>>(
        Q_h, (long)S * D, D, K_h, K_l, (long)S * D, D,
        Sc, (long)S * S, S, D);

    // 5) causal softmax: fp32 Sc -> fp16 P
    softmax_kernel<<<dim3(S, B), blk, 0, stream>>>(Sc, P, S);

    // 6) out = P @ V (K-loop bounded at diagonal, heavy rows first, TN=64)
    gemm2<false, 2, 64><<<dim3(S / TM, D / 64, B), blk, 0, stream>>>(
        P, (long)S * S, S, Vt, nullptr, (long)D * S, S,
        out, (long)S * D, D, S);
}

// Round 3
// 338.385 us; speedup vs baseline: 1.2028x; 1.1680x over previous
//
#include <hip/hip_runtime.h>

typedef float f32x4  __attribute__((ext_vector_type(4)));
typedef _Float16 f16x8  __attribute__((ext_vector_type(8)));
typedef _Float16 f16x4v __attribute__((ext_vector_type(4)));
typedef _Float16 f16x8v __attribute__((ext_vector_type(8)));

__device__ inline void load_lds16(const _Float16* g, _Float16* l) {
    __builtin_amdgcn_global_load_lds((const __attribute__((address_space(1))) void*)g,
                                     (__attribute__((address_space(3))) void*)l, 16, 0, 0);
}

// ---------------------------------------------------------------------------
// convert_h: fp32 -> fp16 (hi only; A-side operands need no lo term)
// ---------------------------------------------------------------------------
__global__ __launch_bounds__(256)
void convert_h(const float* __restrict__ X, _Float16* __restrict__ H, long n4)
{
    long i = (long)blockIdx.x * 256 + threadIdx.x;
    if (i >= n4) return;
    f32x4 v = ((const f32x4*)X)[i];
    f16x4v h;
#pragma unroll
    for (int k = 0; k < 4; ++k) h[k] = (_Float16)v[k];
    ((f16x4v*)H)[i] = h;
}

// ---------------------------------------------------------------------------
// transpose_w3: Wq,Wk -> W2 [2048][2048] fp16 stacked-K (k<1024 hi, k>=1024 lo)
//               Wv -> Wvt [1024][1024] fp16 hi. One dispatch, z = 0/1/2.
// ---------------------------------------------------------------------------
__global__ __launch_bounds__(256)
void transpose_w3(const float* __restrict__ Wq, const float* __restrict__ Wk,
                  const float* __restrict__ Wv,
                  _Float16* __restrict__ W2, _Float16* __restrict__ Wvt, int D)
{
    const int z = blockIdx.z;
    const float* W = (z == 0) ? Wq : (z == 1) ? Wk : Wv;

    __shared__ float t[32][33];
    const int tid = threadIdx.x;
    const int bx = blockIdx.x * 32, by = blockIdx.y * 32;
    const int c = tid & 31, r0 = tid >> 5;
#pragma unroll
    for (int r = r0; r < 32; r += 8)
        t[r][c] = W[(long)(by + r) * D + bx + c];
    __syncthreads();
#pragma unroll
    for (int r = r0; r < 32; r += 8) {
        float v = t[c][r];                       // = W[by+c][bx+r]
        _Float16 h = (_Float16)v;
        if (z < 2) {
            const long nrow = (long)z * D + bx + r;      // stacked Q|K rows
            W2[nrow * 2 * D + by + c]     = h;           // hi at k
            W2[nrow * 2 * D + D + by + c] = (_Float16)(v - (float)h);  // lo at k+D
        } else {
            Wvt[(long)(bx + r) * D + by + c] = h;
        }
    }
}

// ---------------------------------------------------------------------------
// proj8 (v2): 256x256 phase-interleaved projection GEMM.
// R2 reshape: waves 2M x 4N, wave tile 128x64 (m201 geometry). LDS reads per
// CU per K-tile drop 288KB -> 192KB (wave-tile aspect: (Mw+Nw)/(Mw*Nw)).
// B-frags hoisted once per K-tile (8 reads @p0, 32 VGPR); A-frags 4/phase.
// Staging: p0 = B-full (4 loads/thread), p1 = A-full; waits vmcnt(4)@p2,
// vmcnt(0)@p3 (loads 2 phases ~500cyc in flight, L2-resident sources).
//   blocks 0..255 : QK, K'=2048 (A = x duplicated along K via mask,
//                   B = W2 stacked hi|lo). ct<4 -> Q epilogue, else K (hi+lo).
//   blocks 256..383: V, K=1024, transposed epilogue -> Vt [B][D][S].
//   Grid order: all QK (long) first, V (short) last -> tail round is cheap.
// LDS swizzle: 16B granule g of row r lives at g ^ (r&7)  (both-sides, rule
// 21: linear global_load_lds dest + inverse-permuted global source).
// Registers: acc 128 (AGPR) + b 32 + a 16 + addr ~ 200 total of 256 @ 2 w/SIMD.
// ---------------------------------------------------------------------------
__global__ __launch_bounds__(512)
void proj8(const _Float16* __restrict__ x_h, const _Float16* __restrict__ W2,
           const _Float16* __restrict__ Wvt,
           _Float16* __restrict__ Q_h, _Float16* __restrict__ K_h,
           _Float16* __restrict__ K_l, _Float16* __restrict__ Vt,
           const float* __restrict__ bq, const float* __restrict__ bk,
           const float* __restrict__ bv)
{
    constexpr int D = 1024, SEQ = 2048, BK = 64;
    __shared__ __align__(16) _Float16 lds[65536];   // 128 KB: A [0,32768) B [32768,65536)

    const int orig = blockIdx.x;
    const bool isV = orig >= 256;
    int ct, rt, ldb, NT;
    const _Float16* Bb;
    if (!isV) {
        const int x = orig & 7, i = orig >> 3;       // XCD-chunked: rt block of 4, all ct
        rt = x * 4 + (i & 3);  ct = i >> 2;          // ct in [0,8)
        Bb = W2;  ldb = 2 * D; NT = 32;
    } else {
        const int o = orig - 256, x = o & 7, i = o >> 3;
        rt = x * 4 + (i & 3);  ct = i >> 2;          // ct in [0,4)
        Bb = Wvt; ldb = D;     NT = 16;
    }
    const int row0 = rt * 256, col0 = ct * 256;

    const int tid = threadIdx.x;
    const int wave = tid >> 6, lane = tid & 63, l16 = lane & 15, quad = lane >> 4;
    const int wmh = (wave >> 2) * 128;     // M-half this wave owns (rows)
    const int wn  = (wave & 3) * 64;       // 64-col window this wave owns

    _Float16* SA = lds;
    _Float16* SB = lds + 32768;

    // staging: one 128x64 half-tile; phys granule p = q*512+tid (lane-linear),
    // source k pre-permuted by the read-side XOR (involution).
#define STAGEH(gb, ld, grow0, gk, dst)                                          \
    {                                                                           \
        _Pragma("unroll")                                                       \
        for (int q_ = 0; q_ < 2; ++q_) {                                        \
            const int p_ = q_ * 512 + tid;                                      \
            const int rw_ = p_ >> 3;                                            \
            const int kq_ = (p_ & 7) ^ (rw_ & 7);                               \
            load_lds16((gb) + (long)((grow0) + rw_) * (ld) + (gk) + kq_ * 8,    \
                       (dst) + p_ * 8);                                         \
        }                                                                       \
    }

    // prologue: tile 0 fully staged, drained once
    STAGEH(Bb, ldb, col0,       0, SB);
    STAGEH(Bb, ldb, col0 + 128, 0, SB + 8192);
    STAGEH(x_h, D, row0,        0, SA);
    STAGEH(x_h, D, row0 + 128,  0, SA + 8192);
    asm volatile("s_waitcnt vmcnt(0)" ::: "memory");
    __syncthreads();

    f32x4 acc[8][4] = {};

    for (int t = 0; t < NT; ++t) {
        const int cur = t & 1;
        _Float16* Ac = SA + cur * 16384;
        _Float16* Bc = SB + cur * 16384;
        _Float16* An = SA + (cur ^ 1) * 16384;
        _Float16* Bn = SB + (cur ^ 1) * 16384;
        const bool pf = (t + 1 < NT);
        const int kA = ((t + 1) * BK) & (D - 1);   // A duplicated along K'
        const int kB = (t + 1) * BK;

        f16x8 b[4][2];
#pragma unroll
        for (int p = 0; p < 4; ++p) {
            // --- ds reads: b once at p0 (8 reads), a-frags 2 rows x 2 kk (4)
            if (p == 0) {
#pragma unroll
                for (int j = 0; j < 4; ++j) {
                    const int nr = wn + j * 16 + l16;
#pragma unroll
                    for (int kk = 0; kk < 2; ++kk)
                        b[j][kk] = *(const f16x8*)&Bc[nr * 64 +
                                        ((((kk << 2) | quad) ^ (nr & 7)) << 3)];
                }
            }
            f16x8 a[2][2];
#pragma unroll
            for (int il = 0; il < 2; ++il) {
                const int lr = wmh + (p * 2 + il) * 16 + l16;
#pragma unroll
                for (int kk = 0; kk < 2; ++kk)
                    a[il][kk] = *(const f16x8*)&Ac[lr * 64 +
                                    ((((kk << 2) | quad) ^ (lr & 7)) << 3)];
            }
            // --- stage tile t+1: B-full at p0, A-full at p1
            if (pf) {
                if (p == 0) { STAGEH(Bb, ldb, col0,       kB, Bn);
                              STAGEH(Bb, ldb, col0 + 128, kB, Bn + 8192); }
                if (p == 1) { STAGEH(x_h, D, row0,        kA, An);
                              STAGEH(x_h, D, row0 + 128,  kA, An + 8192); }
            }
            // --- waits: B loads (2 phases old) at p2; A loads (2 ph) at p3
            if (p == 2) asm volatile("s_waitcnt vmcnt(4)" ::: "memory");
            if (p == 3) asm volatile("s_waitcnt vmcnt(0)" ::: "memory");
            __builtin_amdgcn_s_barrier();
            asm volatile("s_waitcnt lgkmcnt(0)" ::: "memory");
            __builtin_amdgcn_sched_barrier(0);
            __builtin_amdgcn_s_setprio(1);
#pragma unroll
            for (int il = 0; il < 2; ++il)
#pragma unroll
                for (int j = 0; j < 4; ++j)
#pragma unroll
                    for (int kk = 0; kk < 2; ++kk)
                        acc[p * 2 + il][j] = __builtin_amdgcn_mfma_f32_16x16x32_f16(
                            a[il][kk], b[j][kk], acc[p * 2 + il][j], 0, 0, 0);
            __builtin_amdgcn_s_setprio(0);
            __builtin_amdgcn_s_barrier();
        }
    }

    if (!isV) {
        // ---- Q / K epilogue (tile is entirely Q or entirely K)
        const bool isQ = ct < 4;
        const float* bias = isQ ? bq : bk;
#pragma unroll
        for (int j = 0; j < 4; ++j) {
            const int colg = col0 + wn + j * 16 + l16;
            const int cc = isQ ? colg : colg - D;
            const float bval = bias[cc];
#pragma unroll
            for (int i = 0; i < 8; ++i) {
                const int rb = row0 + wmh + i * 16 + quad * 4;
#pragma unroll
                for (int r = 0; r < 4; ++r) {
                    const float v = acc[i][j][r] + bval;
                    const _Float16 h = (_Float16)v;
                    if (isQ) {
                        Q_h[(long)(rb + r) * D + cc] = h;
                    } else {
                        K_h[(long)(rb + r) * D + cc] = h;
                        K_l[(long)(rb + r) * D + cc] = (_Float16)(v - (float)h);
                    }
                }
            }
        }
    } else {
        // ---- V epilogue: transpose via LDS (reuse all 128 KB), XOR-swizzled
        _Float16* sVt = lds;                 // [256 cols][512B of rows] fp16
#pragma unroll
        for (int j = 0; j < 4; ++j) {
            const int cl = wn + j * 16 + l16;
            const float bval = bv[col0 + cl];
#pragma unroll
            for (int i = 0; i < 8; ++i) {
                f16x4v pk;
#pragma unroll
                for (int r = 0; r < 4; ++r) pk[r] = (_Float16)(acc[i][j][r] + bval);
                const int rowb = wmh * 2 + i * 32 + quad * 8;   // byte in 512B row
                const int sb = cl * 512 + (rowb ^ ((cl & 31) << 4));
                *(f16x4v*)((char*)sVt + sb) = pk;
            }
        }
        __syncthreads();
        const int bb = row0 >> 11;           // tiles never cross batches
        const int s0 = row0 & (SEQ - 1);
        for (int idx = tid; idx < 8192; idx += 512) {
            const int cl = idx >> 5, r8 = idx & 31;
            const int sb = cl * 512 + ((r8 * 16) ^ ((cl & 31) << 4));
            f16x8v v = *(const f16x8v*)((char*)sVt + sb);
            *(f16x8v*)&Vt[((long)bb * D + col0 + cl) * SEQ + s0 + r8 * 8] = v;
        }
    }
#undef STAGEH
}

// ---------------------------------------------------------------------------
// gemm2: C = A @ B^T_layout (fp32 out). A fp16 [M][K] (hi only),
// B fp16 [N][K] hi (+ lo if BLO: 2-term accumulate). TM=128 x TNB, TK=32.
// MODE 1: causal packed triangular grid (x = live-tile id, TNB=64);
// MODE 2: PV, grid (x=rows heavy-first, y=cols), K bounded at (rt+1)*TM.
// ---------------------------------------------------------------------------
constexpr int TM = 128, TK = 32;

template<bool BLO, int MODE, int TNB>
__global__ __launch_bounds__(256)
void gemm2(const _Float16* __restrict__ Ah, long sA, int lda,
           const _Float16* __restrict__ Bh, const _Float16* __restrict__ Bl,
           long sB, int ldb,
           float* __restrict__ Cf, long sC, int ldc, int K)
{
    static_assert(MODE != 1 || TNB == 64, "packed causal decode assumes TNB=64");
    constexpr int NFJ = TNB / 32;
    constexpr int BRNDS = TNB / 64;

    int rt, ct;
    if (MODE == 1) {
        const int t = blockIdx.x;
        rt = (int)((sqrtf(4.0f * t + 1.0f) - 1.0f) * 0.5f);
        while (rt * (rt + 1) > t) --rt;
        while ((rt + 1) * (rt + 2) <= t) ++rt;
        ct = t - rt * (rt + 1);
    } else {
        rt = (gridDim.x - 1) - blockIdx.x;   // heavy rows first
        ct = blockIdx.y;
    }
    const int bz = blockIdx.z;

    const _Float16* gAh = Ah + (long)bz * sA;
    const _Float16* gBh = Bh + (long)bz * sB;
    const _Float16* gBl = BLO ? Bl + (long)bz * sB : nullptr;

    const int row0 = rt * TM, col0 = ct * TNB;
    const int k_end = (MODE == 2) ? min(K, (rt + 1) * TM) : K;

    __shared__ _Float16 sAh[TM * TK];
    __shared__ _Float16 sBh[TNB * TK];
    __shared__ _Float16 sBl[BLO ? TNB * TK : 8];

    const int tid = threadIdx.x;
    const int lane = tid & 63, wave = tid >> 6;
    const int l16 = lane & 15, quad = lane >> 4;
    const int wm = (wave >> 1) * 64, wn = (wave & 1) * (TNB / 2);

    f32x4 acc[4][NFJ] = {};

    for (int k0 = 0; k0 < k_end; k0 += TK) {
#pragma unroll
        for (int rnd = 0; rnd < 2; ++rnd) {
            const int row = rnd * 64 + (tid >> 2);
            const long gA = (long)(row0 + row) * lda + k0 + (tid & 3) * 8;
            load_lds16(gAh + gA, sAh + rnd * 2048 + tid * 8);
        }
#pragma unroll
        for (int rnd = 0; rnd < BRNDS; ++rnd) {
            const int row = rnd * 64 + (tid >> 2);
            const long gB = (long)(col0 + row) * ldb + k0 + (tid & 3) * 8;
            const int lofs = rnd * 2048 + tid * 8;
            load_lds16(gBh + gB, sBh + lofs);
            if (BLO) load_lds16(gBl + gB, sBl + lofs);
        }
        __syncthreads();

        f16x8 a[4], b_h[NFJ];
#pragma unroll
        for (int i = 0; i < 4; ++i)
            a[i] = *(const f16x8*)&sAh[(wm + i * 16 + l16) * TK + (quad << 3)];
#pragma unroll
        for (int j = 0; j < NFJ; ++j)
            b_h[j] = *(const f16x8*)&sBh[(wn + j * 16 + l16) * TK + (quad << 3)];

        if (BLO) {
            f16x8 b_l[NFJ];
#pragma unroll
            for (int j = 0; j < NFJ; ++j)
                b_l[j] = *(const f16x8*)&sBl[(wn + j * 16 + l16) * TK + (quad << 3)];
#pragma unroll
            for (int i = 0; i < 4; ++i)
#pragma unroll
                for (int j = 0; j < NFJ; ++j) {
                    acc[i][j] = __builtin_amdgcn_mfma_f32_16x16x32_f16(a[i], b_h[j], acc[i][j], 0, 0, 0);
                    acc[i][j] = __builtin_amdgcn_mfma_f32_16x16x32_f16(a[i], b_l[j], acc[i][j], 0, 0, 0);
                }
        } else {
#pragma unroll
            for (int i = 0; i < 4; ++i)
#pragma unroll
                for (int j = 0; j < NFJ; ++j)
                    acc[i][j] = __builtin_amdgcn_mfma_f32_16x16x32_f16(a[i], b_h[j], acc[i][j], 0, 0, 0);
        }
        __syncthreads();
    }

    float* cf = Cf + (long)bz * sC;
#pragma unroll
    for (int j = 0; j < NFJ; ++j) {
        const int col = col0 + wn + j * 16 + l16;
#pragma unroll
        for (int i = 0; i < 4; ++i) {
            const int rb = row0 + wm + i * 16 + quad * 4;
#pragma unroll
            for (int r = 0; r < 4; ++r)
                cf[(long)(rb + r) * ldc + col] = acc[i][j][r];
        }
    }
}

// ---------------------------------------------------------------------------
// softmax: causal, fp32 Sc row -> fp16 P row; loads only live 32B chunks,
// writes exactly the columns the PV GEMM will read (ceil((r+1)/128)*128).
// ---------------------------------------------------------------------------
__global__ __launch_bounds__(256)
void softmax_kernel(const float* __restrict__ Sc, _Float16* __restrict__ P, int seq)
{
    const int r = blockIdx.x, b = blockIdx.y;
    const float* row = Sc + ((long)b * seq + r) * seq;
    _Float16* prow = P + ((long)b * seq + r) * seq;
    const int tid = threadIdx.x;
    const int cmax = ((r >> 7) + 1) << 7;
    const int c0 = tid * 8;

    float v[8];
    f32x4 v0, v1;
    if (c0 <= r) {                 // chunk has at least one live column
        const f32x4* rp = (const f32x4*)row;
        v0 = rp[tid * 2];
        v1 = rp[tid * 2 + 1];
    } else {
        v0 = (f32x4)(-3.0e38f);
        v1 = (f32x4)(-3.0e38f);
    }
    float lmax = -3.0e38f;
#pragma unroll
    for (int k = 0; k < 4; ++k) {
        v[k]     = (c0 + k     <= r) ? v0[k] : -3.0e38f;
        v[k + 4] = (c0 + k + 4 <= r) ? v1[k] : -3.0e38f;
    }
#pragma unroll
    for (int k = 0; k < 8; ++k) lmax = fmaxf(lmax, v[k]);

    __shared__ float red[256];
    red[tid] = lmax; __syncthreads();
    for (int s = 128; s > 0; s >>= 1) {
        if (tid < s) red[tid] = fmaxf(red[tid], red[tid + s]);
        __syncthreads();
    }
    const float m = red[0];
    __syncthreads();

    float lsum = 0.0f;
#pragma unroll
    for (int k = 0; k < 8; ++k) {
        float e = (v[k] > -1.0e38f) ? __expf(v[k] - m) : 0.0f;
        v[k] = e;
        lsum += e;
    }
    red[tid] = lsum; __syncthreads();
    for (int s = 128; s > 0; s >>= 1) {
        if (tid < s) red[tid] += red[tid + s];
        __syncthreads();
    }
    const float inv = 1.0f / red[0];

    if (c0 < cmax) {
        f16x8v o;
#pragma unroll
        for (int k = 0; k < 8; ++k) o[k] = (_Float16)(v[k] * inv);
        ((f16x8v*)prow)[tid] = o;
    }
}

// ---------------------------------------------------------------------------
extern "C" void kernel_launch(void* const* d_in, const int* in_sizes, int n_in,
                              void* d_out, int out_size, void* d_ws, size_t ws_size,
                              hipStream_t stream)
{
    constexpr int B = 4, S = 2048, D = 1024;
    constexpr long MB = 1024 * 1024;
    const float* x  = (const float*)d_in[0];
    const float* Wq = (const float*)d_in[1];
    const float* bq = (const float*)d_in[2];
    const float* Wk = (const float*)d_in[3];
    const float* bk = (const float*)d_in[4];
    const float* Wv = (const float*)d_in[5];
    const float* bv = (const float*)d_in[6];
    float* out = (float*)d_out;

    // workspace layout (160 MB; Sc overlaps dead x/W regions)
    char* ws = (char*)d_ws;
    _Float16* x_h   = (_Float16*)(ws + 0);         // 16 MB
    _Float16* W2    = (_Float16*)(ws + 16 * MB);   // 8 MB [2048][2048] hi|lo stacked-K
    _Float16* Wvt_h = (_Float16*)(ws + 24 * MB);   // 2 MB [1024][1024]
    float*    Sc    = (float*)(ws + 0);            // 64 MB, after x/W dead
    _Float16* Q_h   = (_Float16*)(ws + 64 * MB);   // 16 MB [M][1024]
    _Float16* K_h   = (_Float16*)(ws + 80 * MB);   // 16 MB
    _Float16* K_l   = (_Float16*)(ws + 96 * MB);   // 16 MB
    _Float16* Vt    = (_Float16*)(ws + 112 * MB);  // 16 MB [B][D][S]
    _Float16* P     = (_Float16*)(ws + 128 * MB);  // 32 MB [B][S][S]

    const int M = B * S;  // 8192
    dim3 blk(256);

    // 1) convert x -> fp16 hi (A-side needs no lo)
    convert_h<<<(M * D / 4 + 255) / 256, blk, 0, stream>>>(x, x_h, (long)M * D / 4);
    // 2) weight transposes: Wq|Wk hi/lo stacked along K into W2; Wv hi into Wvt
    transpose_w3<<<dim3(D / 32, D / 32, 3), blk, 0, stream>>>(
        Wq, Wk, Wv, W2, Wvt_h, D);

    // 3) phase-interleaved 256x256 projections: blocks 0-255 QK, 256-383 V
    proj8<<<dim3(384), dim3(512), 0, stream>>>(
        x_h, W2, Wvt_h, Q_h, K_h, K_l, Vt, bq, bk, bv);

    // 4) scores = Q_h @ (K_h + K_l)^T (2-term, packed triangular, TN=64) -> fp32
    const int ntiles = (S / TM) * (S / TM + 1);   // 272 live 128x64 tiles
    gemm2<true, 1, 64><<<dim3(ntiles, 1, B), blk, 0, stream>>>(
        Q_h, (long)S * D, D, K_h, K_l, (long)S * D, D,
        Sc, (long)S * S, S, D);

    // 5) causal softmax: fp32 Sc -> fp16 P
    softmax_kernel<<<dim3(S, B), blk, 0, stream>>>(Sc, P, S);

    // 6) out = P @ V (K-loop bounded at diagonal, heavy rows first, TN=64)
    gemm2<false, 2, 64><<<dim3(S / TM, D / 64, B), blk, 0, stream>>>(
        P, (long)S * S, S, Vt, nullptr, (long)D * S, S,
        out, (long)S * D, D, S);
}